// Round 17
// baseline (105.860 us; speedup 1.0000x reference)
//
#include <hip/hip_runtime.h>

#define NROWS 100000
#define IN_DIM 512

typedef __attribute__((ext_vector_type(8))) short short8;
typedef __attribute__((ext_vector_type(4))) float f32x4;

__device__ inline unsigned short f2bf(float f) {
    union { float f; unsigned u; } v; v.f = f;
    unsigned u = v.u;
    return (unsigned short)((u + 0x7FFFu + ((u >> 16) & 1u)) >> 16);
}

// Prepack: B-fragments (bf16) in exact MFMA lane order + fused que bias.
// B = [80 cols x 512 k]: cols 0..63 = Wv, 64..71 = Wq@Wk, 72..79 = 0.
// Bp layout: [t(5)][ks(16)][lane(64)][e(8)] bf16.
__global__ void qg_prepack(const float* __restrict__ Wk, const float* __restrict__ bk,
                           const float* __restrict__ Wq, const float* __restrict__ bq,
                           const float* __restrict__ Wv,
                           unsigned short* __restrict__ Bp, float* __restrict__ qb) {
    int id = blockIdx.x * 256 + threadIdx.x;  // 0..5119
    if (id < 8) {
        float s = bq[id];
        #pragma unroll 4
        for (int j = 0; j < 100; ++j) s += Wq[id * 100 + j] * bk[j];
        qb[id] = s;
    }
    if (id >= 5120) return;
    int lane = id & 63;
    int ks = (id >> 6) & 15;
    int t = id >> 10;
    int c = t * 16 + (lane & 15);
    int kk = ks * 32 + (lane >> 4) * 8;
    short8 pk;
    #pragma unroll
    for (int e = 0; e < 8; ++e) {
        int k2 = kk + e;
        float w;
        if (c < 64) {
            w = Wv[c * IN_DIM + k2];
        } else if (c < 72) {
            float s = 0.f;
            #pragma unroll 4
            for (int j = 0; j < 100; ++j) s += Wq[(c - 64) * 100 + j] * Wk[j * IN_DIM + k2];
            w = s;
        } else {
            w = 0.f;
        }
        pk[e] = (short)f2bf(w);
    }
    ((short8*)Bp)[id] = pk;
}

// Hardcoded register map (reserved via clobbers):
//   A slot0 v48-55, slot1 v56-63, slot2 v64-71
//   B slot0 v72-91, slot1 v92-111, slot2 v112-131
//   offsets v132 (A), v133-137 (B t=0..4);  acc v140-159
#define CA0 "v48","v49","v50","v51","v52","v53","v54","v55"
#define CA1 "v56","v57","v58","v59","v60","v61","v62","v63"
#define CA2 "v64","v65","v66","v67","v68","v69","v70","v71"
#define CB0 "v72","v73","v74","v75","v76","v77","v78","v79","v80","v81","v82","v83","v84","v85","v86","v87","v88","v89","v90","v91"
#define CB1 "v92","v93","v94","v95","v96","v97","v98","v99","v100","v101","v102","v103","v104","v105","v106","v107","v108","v109","v110","v111"
#define CB2 "v112","v113","v114","v115","v116","v117","v118","v119","v120","v121","v122","v123","v124","v125","v126","v127","v128","v129","v130","v131"
#define COFF "v132","v133","v134","v135","v136","v137"
#define CACC "v140","v141","v142","v143","v144","v145","v146","v147","v148","v149","v150","v151","v152","v153","v154","v155","v156","v157","v158","v159"

#define ISSUE(AR0, AR1, B0, B1, B2, B3, B4, CLA, CLB)                          \
    asm volatile(                                                              \
        "global_load_dwordx4 " AR0 ", v132, %0 offset:0\n\t"                   \
        "global_load_dwordx4 " AR1 ", v132, %0 offset:16\n\t"                  \
        "v_add_u32 v132, 0x80, v132\n\t"                                       \
        "global_load_dwordx4 " B0 ", v133, %1 offset:0\n\t"                    \
        "v_add_u32 v133, 0x400, v133\n\t"                                      \
        "global_load_dwordx4 " B1 ", v134, %1 offset:0\n\t"                    \
        "v_add_u32 v134, 0x400, v134\n\t"                                      \
        "global_load_dwordx4 " B2 ", v135, %1 offset:0\n\t"                    \
        "v_add_u32 v135, 0x400, v135\n\t"                                      \
        "global_load_dwordx4 " B3 ", v136, %1 offset:0\n\t"                    \
        "v_add_u32 v136, 0x400, v136\n\t"                                      \
        "global_load_dwordx4 " B4 ", v137, %1 offset:0\n\t"                    \
        "v_add_u32 v137, 0x400, v137"                                          \
        :: "s"(x), "s"(Bp) : "memory", CLA, CLB, COFF)

#define ISSUE0 ISSUE("v[48:51]", "v[52:55]", "v[72:75]", "v[76:79]", "v[80:83]", "v[84:87]", "v[88:91]", CA0, CB0)
#define ISSUE1 ISSUE("v[56:59]", "v[60:63]", "v[92:95]", "v[96:99]", "v[100:103]", "v[104:107]", "v[108:111]", CA1, CB1)
#define ISSUE2 ISSUE("v[64:67]", "v[68:71]", "v[112:115]", "v[116:119]", "v[120:123]", "v[124:127]", "v[128:131]", CA2, CB2)

#define CONS(NW, A0s, A1s, A2s, A3s, AF, B0, B1, B2, B3, B4, CLA)              \
    asm volatile("s_waitcnt vmcnt(" NW ")" ::: "memory");                      \
    asm volatile(                                                              \
        "v_cvt_pk_bf16_f32 " A0s "\n\t"                                        \
        "v_cvt_pk_bf16_f32 " A1s "\n\t"                                        \
        "v_cvt_pk_bf16_f32 " A2s "\n\t"                                        \
        "v_cvt_pk_bf16_f32 " A3s "\n\t"                                        \
        "s_nop 1\n\t"                                                          \
        "v_mfma_f32_16x16x32_bf16 v[140:143], " AF ", " B0 ", v[140:143]\n\t"  \
        "v_mfma_f32_16x16x32_bf16 v[144:147], " AF ", " B1 ", v[144:147]\n\t"  \
        "v_mfma_f32_16x16x32_bf16 v[148:151], " AF ", " B2 ", v[148:151]\n\t"  \
        "v_mfma_f32_16x16x32_bf16 v[152:155], " AF ", " B3 ", v[152:155]\n\t"  \
        "v_mfma_f32_16x16x32_bf16 v[156:159], " AF ", " B4 ", v[156:159]"      \
        ::: "memory", CLA, CACC)

#define CONS0(NW) CONS(NW, "v48, v48, v49", "v49, v50, v51", "v50, v52, v53", "v51, v54, v55", \
                       "v[48:51]", "v[72:75]", "v[76:79]", "v[80:83]", "v[84:87]", "v[88:91]", CA0)
#define CONS1(NW) CONS(NW, "v56, v56, v57", "v57, v58, v59", "v58, v60, v61", "v59, v62, v63", \
                       "v[56:59]", "v[92:95]", "v[96:99]", "v[100:103]", "v[104:107]", "v[108:111]", CA1)
#define CONS2(NW) CONS(NW, "v64, v64, v65", "v65, v66, v67", "v66, v68, v69", "v67, v70, v71", \
                       "v[64:67]", "v[112:115]", "v[116:119]", "v[120:123]", "v[124:127]", "v[128:131]", CA2)

#define ZERO_ACC                                                               \
    asm volatile(                                                              \
        "v_mov_b32 v140, 0\n\tv_mov_b32 v141, 0\n\tv_mov_b32 v142, 0\n\tv_mov_b32 v143, 0\n\t" \
        "v_mov_b32 v144, 0\n\tv_mov_b32 v145, 0\n\tv_mov_b32 v146, 0\n\tv_mov_b32 v147, 0\n\t" \
        "v_mov_b32 v148, 0\n\tv_mov_b32 v149, 0\n\tv_mov_b32 v150, 0\n\tv_mov_b32 v151, 0\n\t" \
        "v_mov_b32 v152, 0\n\tv_mov_b32 v153, 0\n\tv_mov_b32 v154, 0\n\tv_mov_b32 v155, 0\n\t" \
        "v_mov_b32 v156, 0\n\tv_mov_b32 v157, 0\n\tv_mov_b32 v158, 0\n\tv_mov_b32 v159, 0\n\t" \
        "s_nop 1" ::: CACC)

#define EXTRACT_ACC(ac)                                                        \
    asm volatile("s_nop 7\n\ts_nop 7\n\ts_nop 7");                             \
    asm volatile("v_mov_b32 %0, v140" : "=v"(ac[0][0]));                       \
    asm volatile("v_mov_b32 %0, v141" : "=v"(ac[0][1]));                       \
    asm volatile("v_mov_b32 %0, v142" : "=v"(ac[0][2]));                       \
    asm volatile("v_mov_b32 %0, v143" : "=v"(ac[0][3]));                       \
    asm volatile("v_mov_b32 %0, v144" : "=v"(ac[1][0]));                       \
    asm volatile("v_mov_b32 %0, v145" : "=v"(ac[1][1]));                       \
    asm volatile("v_mov_b32 %0, v146" : "=v"(ac[1][2]));                       \
    asm volatile("v_mov_b32 %0, v147" : "=v"(ac[1][3]));                       \
    asm volatile("v_mov_b32 %0, v148" : "=v"(ac[2][0]));                       \
    asm volatile("v_mov_b32 %0, v149" : "=v"(ac[2][1]));                       \
    asm volatile("v_mov_b32 %0, v150" : "=v"(ac[2][2]));                       \
    asm volatile("v_mov_b32 %0, v151" : "=v"(ac[2][3]));                       \
    asm volatile("v_mov_b32 %0, v152" : "=v"(ac[3][0]));                       \
    asm volatile("v_mov_b32 %0, v153" : "=v"(ac[3][1]));                       \
    asm volatile("v_mov_b32 %0, v154" : "=v"(ac[3][2]));                       \
    asm volatile("v_mov_b32 %0, v155" : "=v"(ac[3][3]));                       \
    asm volatile("v_mov_b32 %0, v156" : "=v"(ac[4][0]));                       \
    asm volatile("v_mov_b32 %0, v157" : "=v"(ac[4][1]));                       \
    asm volatile("v_mov_b32 %0, v158" : "=v"(ac[4][2]));                       \
    asm volatile("v_mov_b32 %0, v159" : "=v"(ac[4][3]))

// Main: 256 threads = 4 waves, each wave processes TWO 16-row tiles.
// Tile-2's prologue loads are issued before tile-1's stores; tile-1's 32 NT
// stores are interleaved 2-per-step into tile-2's consume ladder, always
// YOUNGER in the vmcnt FIFO than the load being waited on -> reads and writes
// flow concurrently (full-duplex HBM) instead of phase-synchronized bursts.
__global__ __launch_bounds__(256, 2) void qg_main(const float* __restrict__ x,
                                                  const float* __restrict__ bv,
                                                  const unsigned short* __restrict__ Bp,
                                                  const float* __restrict__ qb,
                                                  float* __restrict__ out) {
    __shared__ float vlds[4][16][68];
    __shared__ float wlds[4][16][8];
    const int tid = threadIdx.x;
    const int w = tid >> 6;
    const int lane = tid & 63;
    const int g = lane >> 4;
    const int cl = lane & 15;
    const int rb1 = blockIdx.x * 128 + w * 16;   // 782*128 = 100096 covers N
    const int rb2 = rb1 + 64;

    const unsigned voffA1 = (unsigned)(min(rb1 + cl, NROWS - 1) * 512 + g * 8) * 4u;
    const unsigned voffA2 = (unsigned)(min(rb2 + cl, NROWS - 1) * 512 + g * 8) * 4u;
    const unsigned voffB = (unsigned)lane * 16u;

    float bvr[4];
    #pragma unroll
    for (int t = 0; t < 4; ++t) bvr[t] = bv[t * 16 + cl];
    float qbr = qb[cl & 7];
    asm volatile("s_waitcnt vmcnt(0)" ::: "memory");

    // Init offsets (tile 1) + zero accumulators.
    asm volatile(
        "v_mov_b32 v132, %0\n\tv_mov_b32 v133, %1\n\tv_mov_b32 v134, %2\n\t"
        "v_mov_b32 v135, %3\n\tv_mov_b32 v136, %4\n\tv_mov_b32 v137, %5"
        :: "v"(voffA1), "v"(voffB), "v"(voffB + 16384u), "v"(voffB + 32768u),
           "v"(voffB + 49152u), "v"(voffB + 65536u) : COFF);
    ZERO_ACC;

    // ---- Tile 1 ladder (R14-proven), tail overlapped with tile-2 issues ----
    ISSUE0; ISSUE1; ISSUE2;
    CONS0("14"); ISSUE0;   // S=0
    CONS1("14"); ISSUE1;   // S=1
    CONS2("14"); ISSUE2;   // S=2
    CONS0("14"); ISSUE0;   // S=3
    CONS1("14"); ISSUE1;   // S=4
    CONS2("14"); ISSUE2;   // S=5
    CONS0("14"); ISSUE0;   // S=6
    CONS1("14"); ISSUE1;   // S=7
    CONS2("14"); ISSUE2;   // S=8
    CONS0("14"); ISSUE0;   // S=9
    CONS1("14"); ISSUE1;   // S=10
    CONS2("14"); ISSUE2;   // S=11
    CONS0("14"); ISSUE0;   // S=12 (issues b15)
    CONS1("14");           // S=13
    // Re-point offsets at tile 2, then keep the FIFO fed across the epilogue.
    asm volatile(
        "v_mov_b32 v132, %0\n\tv_mov_b32 v133, %1\n\tv_mov_b32 v134, %2\n\t"
        "v_mov_b32 v135, %3\n\tv_mov_b32 v136, %4\n\tv_mov_b32 v137, %5"
        :: "v"(voffA2), "v"(voffB), "v"(voffB + 16384u), "v"(voffB + 32768u),
           "v"(voffB + 49152u), "v"(voffB + 65536u) : COFF);
    ISSUE1;                // t2 b0 -> slot1
    CONS2("14"); ISSUE2;   // S=14 ; t2 b1 -> slot2
    CONS0("14"); ISSUE0;   // S=15 ; t2 b2 -> slot0

    float ac[5][4];
    EXTRACT_ACC(ac);
    ZERO_ACC;

    // ---- Tile 1 epilogue into LDS (no VMEM) ----
    #pragma unroll
    for (int t = 0; t < 4; ++t) {
        #pragma unroll
        for (int r = 0; r < 4; ++r)
            vlds[w][g * 4 + r][t * 16 + cl] = ac[t][r] + bvr[t];
    }
    if (cl < 8) {
        #pragma unroll
        for (int r = 0; r < 4; ++r)
            wlds[w][g * 4 + r][cl] = ac[4][r] + qbr;
    }
    asm volatile("s_waitcnt lgkmcnt(0)" ::: "memory");
    if (lane < 16) {
        float q[8];
        float m = -1e30f;
        #pragma unroll
        for (int k = 0; k < 8; ++k) { q[k] = wlds[w][lane][k]; m = fmaxf(m, q[k]); }
        float ssum = 0.f;
        #pragma unroll
        for (int k = 0; k < 8; ++k) { q[k] = __expf(q[k] - m); ssum += q[k]; }
        float inv = 1.f / ssum;
        #pragma unroll
        for (int k = 0; k < 8; ++k) wlds[w][lane][k] = q[k] * inv;
    }
    asm volatile("s_waitcnt lgkmcnt(0)" ::: "memory");

    // Two NT stores of tile-1 row S (full 512-float row per step).
#define STORE2(S) do {                                                         \
        int srow_ = min(rb1 + (S), NROWS - 1);                                 \
        float wgt0_ = wlds[w][S][lane >> 4];                                   \
        float wgt1_ = wlds[w][S][4 + (lane >> 4)];                             \
        float4 vv_ = *(const float4*)&vlds[w][S][(lane & 15) * 4];             \
        f32x4 o0_, o1_;                                                        \
        o0_[0] = wgt0_ * vv_.x; o0_[1] = wgt0_ * vv_.y;                        \
        o0_[2] = wgt0_ * vv_.z; o0_[3] = wgt0_ * vv_.w;                        \
        o1_[0] = wgt1_ * vv_.x; o1_[1] = wgt1_ * vv_.y;                        \
        o1_[2] = wgt1_ * vv_.z; o1_[3] = wgt1_ * vv_.w;                        \
        unsigned off0_ = (unsigned)srow_ * 2048u + (unsigned)lane * 16u;       \
        asm volatile("global_store_dwordx4 %0, %1, %2 nt"                      \
                     :: "v"(off0_), "v"(o0_), "s"(out) : "memory");            \
        asm volatile("global_store_dwordx4 %0, %1, %2 offset:1024 nt"          \
                     :: "v"(off0_), "v"(o1_), "s"(out) : "memory");            \
    } while (0)

    // ---- Tile 2 ladder with tile-1 stores interleaved (stores are younger
    // than every waited-on load; literals account for them exactly) ----
    STORE2(0);  CONS1("16"); ISSUE1;
    STORE2(1);  CONS2("18"); ISSUE2;
    STORE2(2);  CONS0("20"); ISSUE0;
    STORE2(3);  CONS1("20"); ISSUE1;
    STORE2(4);  CONS2("20"); ISSUE2;
    STORE2(5);  CONS0("20"); ISSUE0;
    STORE2(6);  CONS1("20"); ISSUE1;
    STORE2(7);  CONS2("20"); ISSUE2;
    STORE2(8);  CONS0("20"); ISSUE0;
    STORE2(9);  CONS1("20"); ISSUE1;
    STORE2(10); CONS2("20"); ISSUE2;
    STORE2(11); CONS0("20"); ISSUE0;
    STORE2(12); CONS1("20"); ISSUE1;   // issues t2 b15
    STORE2(13); CONS2("20");
    STORE2(14); CONS0("13");
    STORE2(15); CONS1("6");
#undef STORE2

    EXTRACT_ACC(ac);

    // ---- Tile 2 epilogue ----
    #pragma unroll
    for (int t = 0; t < 4; ++t) {
        #pragma unroll
        for (int r = 0; r < 4; ++r)
            vlds[w][g * 4 + r][t * 16 + cl] = ac[t][r] + bvr[t];
    }
    if (cl < 8) {
        #pragma unroll
        for (int r = 0; r < 4; ++r)
            wlds[w][g * 4 + r][cl] = ac[4][r] + qbr;
    }
    asm volatile("s_waitcnt lgkmcnt(0)" ::: "memory");
    if (lane < 16) {
        float q[8];
        float m = -1e30f;
        #pragma unroll
        for (int k = 0; k < 8; ++k) { q[k] = wlds[w][lane][k]; m = fmaxf(m, q[k]); }
        float ssum = 0.f;
        #pragma unroll
        for (int k = 0; k < 8; ++k) { q[k] = __expf(q[k] - m); ssum += q[k]; }
        float inv = 1.f / ssum;
        #pragma unroll
        for (int k = 0; k < 8; ++k) wlds[w][lane][k] = q[k] * inv;
    }
    asm volatile("s_waitcnt lgkmcnt(0)" ::: "memory");

    f32x4* outp = (f32x4*)out;
    #pragma unroll
    for (int it = 0; it < 32; ++it) {
        int idx = it * 64 + lane;
        int row = idx >> 7;
        int j = idx & 127;
        int srow = min(rb2 + row, NROWS - 1);   // clamped duplicate writes are
        float wgt = wlds[w][row][j >> 4];       // bit-identical -> benign
        float4 vv = *(const float4*)&vlds[w][row][(j & 15) * 4];
        f32x4 o;
        o[0] = wgt * vv.x; o[1] = wgt * vv.y; o[2] = wgt * vv.z; o[3] = wgt * vv.w;
        __builtin_nontemporal_store(o, &outp[(size_t)srow * 128 + j]);
    }
}

extern "C" void kernel_launch(void* const* d_in, const int* in_sizes, int n_in,
                              void* d_out, int out_size, void* d_ws, size_t ws_size,
                              hipStream_t stream) {
    const float* x  = (const float*)d_in[0];
    const float* Wk = (const float*)d_in[1];
    const float* bk = (const float*)d_in[2];
    const float* Wq = (const float*)d_in[3];
    const float* bq = (const float*)d_in[4];
    const float* Wv = (const float*)d_in[5];
    const float* bv = (const float*)d_in[6];
    float* out = (float*)d_out;

    unsigned short* Bp = (unsigned short*)d_ws;          // 81920 B
    float* qb = (float*)((char*)d_ws + 81920);           // 8 floats

    qg_prepack<<<20, 256, 0, stream>>>(Wk, bk, Wq, bq, Wv, Bp, qb);
    qg_main<<<782, 256, 0, stream>>>(x, bv, Bp, qb, out);
}